// Round 4
// baseline (334.197 us; speedup 1.0000x reference)
//
#include <hip/hip_runtime.h>
#include <stdint.h>

#define N_NODES 10000
#define N_EDGES 320000
#define D_IN    512
#define D_HID   2048
#define N_CLS   40
#define MP1     10112   // H1 rows (79*128)
#define MP2     10240   // Pb padded rows (gemm1 reads up to row 10127)
#define MBLK    1264    // rows per gemm1 M-block (8 blocks * 1264 = 10112)

typedef float f32x4  __attribute__((ext_vector_type(4)));
typedef short bf16x8 __attribute__((ext_vector_type(8)));
typedef unsigned short us8 __attribute__((ext_vector_type(8)));

__device__ inline unsigned short f2bf(float f){
  unsigned int u = __float_as_uint(f);
  u += 0x7fffu + ((u >> 16) & 1u);   // round-to-nearest-even
  return (unsigned short)(u >> 16);
}

__device__ inline float bf2f(unsigned short h){
  return __uint_as_float(((unsigned int)h) << 16);
}

__device__ inline void gl_lds16(const void* g, void* l){
  __builtin_amdgcn_global_load_lds((const __attribute__((address_space(1))) void*)g,
                                   (__attribute__((address_space(3))) void*)l, 16, 0, 0);
}

// ---------------- graph preprocessing ----------------
__global__ void k_count(const int* __restrict__ ei, int* __restrict__ deg){
  int e = blockIdx.x*256 + threadIdx.x;
  if (e < N_EDGES) atomicAdd(&deg[ei[N_EDGES + e]], 1);
}

__global__ void k_scan(const int* __restrict__ deg, int* __restrict__ offsets,
                       int* __restrict__ cursor, float* __restrict__ dinv){
  __shared__ int sums[1024];
  const int t = threadIdx.x;
  const int CH = 10;
  int base = t*CH;
  int local[CH]; int s = 0;
  for (int j = 0; j < CH; j++){
    int v = (base + j < N_NODES) ? deg[base + j] : 0;
    local[j] = s; s += v;
    if (base + j < N_NODES) dinv[base + j] = rsqrtf((float)v + 1.0f);
  }
  sums[t] = s;
  __syncthreads();
  for (int off = 1; off < 1024; off <<= 1){
    int v = (t >= off) ? sums[t - off] : 0;
    __syncthreads();
    sums[t] += v;
    __syncthreads();
  }
  int pre = (t > 0) ? sums[t-1] : 0;
  for (int j = 0; j < CH; j++){
    int idx = base + j;
    if (idx < N_NODES){ int o = pre + local[j]; offsets[idx] = o; cursor[idx] = o; }
  }
}

__global__ void k_fill(const int* __restrict__ ei, int* __restrict__ cursor, int* __restrict__ csr_src){
  int e = blockIdx.x*256 + threadIdx.x;
  if (e < N_EDGES){
    int s = ei[e], d = ei[N_EDGES + e];
    int pos = atomicAdd(&cursor[d], 1);
    csr_src[pos] = s;
  }
}

// ---------------- x -> bf16 ----------------
__global__ void k_castx(const float* __restrict__ x, unsigned short* __restrict__ Xb){
  int idx = blockIdx.x*256 + threadIdx.x;
  const f32x4* x4 = (const f32x4*)x;
  f32x4 a = x4[idx*2], b = x4[idx*2+1];
  us8 o;
  o[0]=f2bf(a.x); o[1]=f2bf(a.y); o[2]=f2bf(a.z); o[3]=f2bf(a.w);
  o[4]=f2bf(b.x); o[5]=f2bf(b.y); o[6]=f2bf(b.z); o[7]=f2bf(b.w);
  *(us8*)(Xb + (size_t)idx*8) = o;
}

// ---------------- propagate(Xb) -> Pb, one wave/node, 128-feature slice ----------------
// Feature-split across 4 launches so each launch's Xb slice (10000*256B=2.56MB)
// is per-XCD-L2 resident.
__global__ __launch_bounds__(256) void k_gather1(const unsigned short* __restrict__ Xb,
                          const int* __restrict__ csr_src,
                          const int* __restrict__ offsets, const int* __restrict__ deg,
                          const float* __restrict__ dinv, unsigned short* __restrict__ Pb,
                          int col0){
  const int w    = threadIdx.x >> 6;
  const int lane = threadIdx.x & 63;
  const int i    = blockIdx.x*4 + w;       // 2500 blocks x 4 waves
  const float di = dinv[i];
  const unsigned short* Xc = Xb + col0 + lane*2;
  unsigned int xi = *(const unsigned int*)(Xc + (size_t)i*D_IN);
  const float dii = di*di;
  float a0 = dii * bf2f((unsigned short)(xi & 0xffffu));
  float a1 = dii * bf2f((unsigned short)(xi >> 16));
  const int start = offsets[i], cnt = deg[i];
  for (int c0 = 0; c0 < cnt; c0 += 64){
    int m = cnt - c0; if (m > 64) m = 64;
    int s = 0; float cf = 0.0f;
    if (lane < m){ s = csr_src[start + c0 + lane]; cf = dinv[s]*di; }
    for (int j = 0; j < m; j++){
      int   sj = __shfl(s, j);
      float cj = __shfl(cf, j);
      unsigned int xr = *(const unsigned int*)(Xc + (size_t)sj*D_IN);
      a0 += cj * bf2f((unsigned short)(xr & 0xffffu));
      a1 += cj * bf2f((unsigned short)(xr >> 16));
    }
  }
  unsigned int o = (unsigned int)f2bf(a0) | ((unsigned int)f2bf(a1) << 16);
  *(unsigned int*)(Pb + (size_t)i*D_IN + col0 + lane*2) = o;
}

// ---------------- weight prep ----------------
__global__ void k_transposeW1(const float* __restrict__ W1, unsigned short* __restrict__ Wt1){
  __shared__ float tile[32][33];
  const int n0 = blockIdx.x*32, k0 = blockIdx.y*32;
  const int tx = threadIdx.x, ty = threadIdx.y;
  for (int i = 0; i < 32; i += 8)
    tile[ty+i][tx] = W1[(size_t)(k0+ty+i)*D_HID + n0+tx];
  __syncthreads();
  for (int i = 0; i < 32; i += 8)
    Wt1[(size_t)(n0+ty+i)*D_IN + k0+tx] = f2bf(tile[tx][ty+i]);
}

__global__ void k_convW2(const float* __restrict__ W2, unsigned short* __restrict__ Wt2){
  int idx = blockIdx.x*256 + threadIdx.x;
  if (idx < 48*D_HID){
    int n = idx >> 11, k = idx & (D_HID-1);
    Wt2[idx] = (n < N_CLS) ? f2bf(W2[k*N_CLS + n]) : (unsigned short)0;
  }
}

// ---------------- GEMM1 v2: barrier-free K-loop ----------------
// Block = (M-block mblk of 1264 rows) x (64-col B panel). B panel staged once
// into LDS (XOR-swizzled: chunk c of row n at position c^(n&7)); 8 waves then
// run private K-loops: A frags global->VGPR (prefetched), B frags from LDS,
// no __syncthreads after staging. grid.x = M so XCD j hosts only M-block j
// (A slice 1.26MB -> L2 resident).
__global__ __launch_bounds__(512, 4) void k_gemm1(const unsigned short* __restrict__ Pb,
                                                  const unsigned short* __restrict__ Wt1,
                                                  const float* __restrict__ b1,
                                                  unsigned short* __restrict__ H1){
  __shared__ short Bs[64*512];           // 64 KB
  const int t    = threadIdx.x;
  const int lane = t & 63;
  const int wid  = t >> 6;               // 8 waves
  const int mblk = blockIdx.x;           // 0..7
  const int n0   = blockIdx.y*64;        // 0..31 panels
  // stage B panel: wave w stages rows w*8 .. w*8+7 (one row per wave-op)
  for (int r = 0; r < 8; r++){
    int n = wid*8 + r;
    int c = lane ^ (n & 7);              // swizzled source chunk (16B units)
    gl_lds16(Wt1 + (size_t)(n0 + n)*D_IN + c*8, Bs + n*512 + lane*8);
  }
  __syncthreads();

  const int fr = lane & 15;
  const int q  = lane >> 4;
  const int bsw = fr & 7;                // B swizzle key

  for (int p = 0; p < 3; p++){
    if (p*512 + wid*64 >= MBLK) break;   // wave-uniform
    const int mrow0 = mblk*MBLK + p*512 + wid*64;
    const unsigned short* Ap = Pb + (size_t)(mrow0 + fr)*D_IN + q*8;
    f32x4 acc[4][4] = {};
    bf16x8 ac[4], an[4];
    #pragma unroll
    for (int i = 0; i < 4; i++) ac[i] = *(const bf16x8*)(Ap + i*16*D_IN);
    for (int ks = 0; ks < 16; ks++){
      if (ks < 15){
        #pragma unroll
        for (int i = 0; i < 4; i++) an[i] = *(const bf16x8*)(Ap + i*16*D_IN + (ks+1)*32);
      }
      bf16x8 b[4];
      #pragma unroll
      for (int j = 0; j < 4; j++)
        b[j] = *(const bf16x8*)(Bs + (j*16 + fr)*512 + (((ks*4 + q) ^ bsw)*8));
      #pragma unroll
      for (int i = 0; i < 4; i++)
        #pragma unroll
        for (int j = 0; j < 4; j++)
          acc[i][j] = __builtin_amdgcn_mfma_f32_16x16x32_bf16(ac[i], b[j], acc[i][j], 0, 0, 0);
      #pragma unroll
      for (int i = 0; i < 4; i++) ac[i] = an[i];
    }
    // epilogue
    #pragma unroll
    for (int j = 0; j < 4; j++){
      int col = n0 + j*16 + fr;
      float bias = b1[col];
      #pragma unroll
      for (int i = 0; i < 4; i++){
        int rbase = mrow0 + i*16 + q*4;
        f32x4 v = acc[i][j];
        #pragma unroll
        for (int r = 0; r < 4; r++){
          int row = rbase + r;
          if (row < N_NODES){
            float h = fmaxf(v[r] + bias, 0.0f);
            H1[(size_t)row*D_HID + col] = f2bf(h);
          }
        }
      }
    }
  }
}

// ---------------- GEMM2: G = H1 @ W2 (split-K across 4 waves, atomic) ----------------
__global__ __launch_bounds__(256) void k_gemm2(const unsigned short* __restrict__ H1,
                                               const unsigned short* __restrict__ Wt2,
                                               float* __restrict__ G){
  __shared__ short As[4][64*32];
  __shared__ short Bs[4][48*32];
  const int t    = threadIdx.x;
  const int lane = t & 63;
  const int wid  = t >> 6;
  const int m0   = blockIdx.x*64;
  const int lrow = lane >> 2;
  const int lkof = ((lane & 3) ^ ((lane >> 3) & 3))*8;
  const int fr   = lane & 15;
  const int sq8  = ((lane >> 4) ^ ((fr >> 1) & 3))*8;
  const int fq   = lane >> 4;
  f32x4 acc[4][3] = {};
  for (int it = 0; it < 16; it++){
    const int kb = wid*512 + it*32;
    #pragma unroll
    for (int c = 0; c < 4; c++)
      gl_lds16(H1 + (size_t)(m0 + c*16 + lrow)*D_HID + kb + lkof, &As[wid][c*512 + lane*8]);
    #pragma unroll
    for (int c = 0; c < 3; c++)
      gl_lds16(Wt2 + (size_t)(c*16 + lrow)*D_HID + kb + lkof, &Bs[wid][c*512 + lane*8]);
    __syncthreads();
    bf16x8 a[4], b[3];
    #pragma unroll
    for (int i = 0; i < 4; i++) a[i] = *(const bf16x8*)(&As[wid][(i*16 + fr)*32 + sq8]);
    #pragma unroll
    for (int j = 0; j < 3; j++) b[j] = *(const bf16x8*)(&Bs[wid][(j*16 + fr)*32 + sq8]);
    #pragma unroll
    for (int i = 0; i < 4; i++)
      #pragma unroll
      for (int j = 0; j < 3; j++)
        acc[i][j] = __builtin_amdgcn_mfma_f32_16x16x32_bf16(a[i], b[j], acc[i][j], 0, 0, 0);
    __syncthreads();
  }
  #pragma unroll
  for (int j = 0; j < 3; j++){
    int col = j*16 + fr;
    #pragma unroll
    for (int i = 0; i < 4; i++){
      int rbase = m0 + i*16 + fq*4;
      f32x4 v = acc[i][j];
      #pragma unroll
      for (int r = 0; r < 4; r++){
        int row = rbase + r;
        if (row < N_NODES && col < N_CLS)
          atomicAdd(&G[row*N_CLS + col], v[r]);
      }
    }
  }
}

// ---------------- propagate(G) + b2 -> out ----------------
__global__ void k_gather2(const float* __restrict__ G, const int* __restrict__ csr_src,
                          const int* __restrict__ offsets, const int* __restrict__ deg,
                          const float* __restrict__ dinv, const float* __restrict__ b2,
                          float* __restrict__ out){
  __shared__ int   ssrc[64];
  __shared__ float scoef[64];
  const int i = blockIdx.x;
  const int t = threadIdx.x;
  const float di = dinv[i];
  const int start = offsets[i], cnt = deg[i];
  float acc = 0.0f;
  if (t < N_CLS) acc = di*di * G[i*N_CLS + t];
  for (int c0 = 0; c0 < cnt; c0 += 64){
    int m = cnt - c0; if (m > 64) m = 64;
    if (t < m){
      int s = csr_src[start + c0 + t];
      ssrc[t] = s; scoef[t] = dinv[s]*di;
    }
    __syncthreads();
    if (t < N_CLS)
      for (int j = 0; j < m; j++)
        acc += scoef[j] * G[ssrc[j]*N_CLS + t];
    __syncthreads();
  }
  if (t < N_CLS) out[i*N_CLS + t] = acc + b2[t];
}

extern "C" void kernel_launch(void* const* d_in, const int* in_sizes, int n_in,
                              void* d_out, int out_size, void* d_ws, size_t ws_size,
                              hipStream_t stream){
  const float* x  = (const float*)d_in[0];
  const int*   ei = (const int*)d_in[1];
  const float* W1 = (const float*)d_in[2];
  const float* b1 = (const float*)d_in[3];
  const float* W2 = (const float*)d_in[4];
  const float* b2 = (const float*)d_in[5];
  float* out = (float*)d_out;

  char* ws = (char*)d_ws;
  size_t off = 0;
  auto alloc = [&](size_t bytes) -> void* {
    void* p = ws + off; off += (bytes + 255) & ~(size_t)255; return p;
  };
  int*   deg     = (int*)alloc((size_t)N_NODES*4);
  float* dinv    = (float*)alloc((size_t)N_NODES*4);
  int*   offsets = (int*)alloc((size_t)N_NODES*4);
  int*   cursor  = (int*)alloc((size_t)N_NODES*4);
  int*   csr     = (int*)alloc((size_t)N_EDGES*4);
  unsigned short* Xb  = (unsigned short*)alloc((size_t)N_NODES*D_IN*2);
  unsigned short* Pb  = (unsigned short*)alloc((size_t)MP2*D_IN*2);
  unsigned short* Wt1 = (unsigned short*)alloc((size_t)D_HID*D_IN*2);
  unsigned short* Wt2 = (unsigned short*)alloc((size_t)48*D_HID*2);
  unsigned short* H1  = (unsigned short*)alloc((size_t)MP1*D_HID*2);
  float* G = (float*)alloc((size_t)N_NODES*N_CLS*4);

  hipMemsetAsync(deg, 0, (size_t)N_NODES*4, stream);
  hipMemsetAsync(G,   0, (size_t)N_NODES*N_CLS*4, stream);

  k_count<<<(N_EDGES+255)/256, 256, 0, stream>>>(ei, deg);
  k_scan<<<1, 1024, 0, stream>>>(deg, offsets, cursor, dinv);
  k_fill<<<(N_EDGES+255)/256, 256, 0, stream>>>(ei, cursor, csr);
  k_castx<<<(N_NODES*D_IN/8 + 255)/256, 256, 0, stream>>>(x, Xb);
  k_gather1<<<N_NODES/4, 256, 0, stream>>>(Xb, csr, offsets, deg, dinv, Pb, 0);
  k_gather1<<<N_NODES/4, 256, 0, stream>>>(Xb, csr, offsets, deg, dinv, Pb, 128);
  k_gather1<<<N_NODES/4, 256, 0, stream>>>(Xb, csr, offsets, deg, dinv, Pb, 256);
  k_gather1<<<N_NODES/4, 256, 0, stream>>>(Xb, csr, offsets, deg, dinv, Pb, 384);
  k_transposeW1<<<dim3(D_HID/32, D_IN/32), dim3(32,8), 0, stream>>>(W1, Wt1);
  k_convW2<<<(48*D_HID+255)/256, 256, 0, stream>>>(W2, Wt2);
  k_gemm1<<<dim3(8, 32), 512, 0, stream>>>(Pb, Wt1, b1, H1);
  k_gemm2<<<(N_NODES+63)/64, 256, 0, stream>>>(H1, Wt2, G);
  k_gather2<<<N_NODES, 64, 0, stream>>>(G, csr, offsets, deg, dinv, b2, out);
}

// Round 5
// 279.155 us; speedup vs baseline: 1.1972x; 1.1972x over previous
//
#include <hip/hip_runtime.h>
#include <stdint.h>

#define N_NODES 10000
#define N_EDGES 320000
#define D_IN    512
#define D_HID   2048
#define N_CLS   40
#define MP1     10112   // H1 rows (79*128)
#define MP2     10240   // Pb padded rows (gemm1 reads 20*512 rows)

typedef float f32x4  __attribute__((ext_vector_type(4)));
typedef short bf16x8 __attribute__((ext_vector_type(8)));
typedef unsigned short us8 __attribute__((ext_vector_type(8)));

__device__ inline unsigned short f2bf(float f){
  unsigned int u = __float_as_uint(f);
  u += 0x7fffu + ((u >> 16) & 1u);   // round-to-nearest-even
  return (unsigned short)(u >> 16);
}

__device__ inline float bf2f(unsigned short h){
  return __uint_as_float(((unsigned int)h) << 16);
}

__device__ inline void gl_lds16(const void* g, void* l){
  __builtin_amdgcn_global_load_lds((const __attribute__((address_space(1))) void*)g,
                                   (__attribute__((address_space(3))) void*)l, 16, 0, 0);
}

// ---------------- fused: x->bf16 cast + degree count ----------------
__global__ void k_prep0(const float* __restrict__ x, unsigned short* __restrict__ Xb,
                        const int* __restrict__ ei, int* __restrict__ deg){
  if (blockIdx.x < 2500){
    int idx = blockIdx.x*256 + threadIdx.x;     // 640000 groups of 8
    const f32x4* x4 = (const f32x4*)x;
    f32x4 a = x4[idx*2], b = x4[idx*2+1];
    us8 o;
    o[0]=f2bf(a.x); o[1]=f2bf(a.y); o[2]=f2bf(a.z); o[3]=f2bf(a.w);
    o[4]=f2bf(b.x); o[5]=f2bf(b.y); o[6]=f2bf(b.z); o[7]=f2bf(b.w);
    *(us8*)(Xb + (size_t)idx*8) = o;
  } else {
    int e = (blockIdx.x - 2500)*256 + threadIdx.x;
    if (e < N_EDGES) atomicAdd(&deg[ei[N_EDGES + e]], 1);
  }
}

__global__ void k_scan(const int* __restrict__ deg, int* __restrict__ offsets,
                       int* __restrict__ cursor, float* __restrict__ dinv){
  __shared__ int sums[1024];
  const int t = threadIdx.x;
  const int CH = 10;
  int base = t*CH;
  int local[CH]; int s = 0;
  for (int j = 0; j < CH; j++){
    int v = (base + j < N_NODES) ? deg[base + j] : 0;
    local[j] = s; s += v;
    if (base + j < N_NODES) dinv[base + j] = rsqrtf((float)v + 1.0f);
  }
  sums[t] = s;
  __syncthreads();
  for (int off = 1; off < 1024; off <<= 1){
    int v = (t >= off) ? sums[t - off] : 0;
    __syncthreads();
    sums[t] += v;
    __syncthreads();
  }
  int pre = (t > 0) ? sums[t-1] : 0;
  for (int j = 0; j < CH; j++){
    int idx = base + j;
    if (idx < N_NODES){ int o = pre + local[j]; offsets[idx] = o; cursor[idx] = o; }
  }
}

__global__ void k_fill(const int* __restrict__ ei, int* __restrict__ cursor, int* __restrict__ csr_src){
  int e = blockIdx.x*256 + threadIdx.x;
  if (e < N_EDGES){
    int s = ei[e], d = ei[N_EDGES + e];
    int pos = atomicAdd(&cursor[d], 1);
    csr_src[pos] = s;
  }
}

// ---------------- fused weight prep: W1 transpose->bf16, W2 pad/transpose->bf16 ----------------
__global__ void k_prepW(const float* __restrict__ W1, unsigned short* __restrict__ Wt1,
                        const float* __restrict__ W2, unsigned short* __restrict__ Wt2){
  if (blockIdx.x < 1024){
    __shared__ float tile[32][33];
    const int n0 = (blockIdx.x & 63)*32, k0 = (blockIdx.x >> 6)*32;
    const int tx = threadIdx.x & 31, ty = threadIdx.x >> 5;   // 32 x 8
    for (int i = 0; i < 32; i += 8)
      tile[ty+i][tx] = W1[(size_t)(k0+ty+i)*D_HID + n0+tx];
    __syncthreads();
    for (int i = 0; i < 32; i += 8)
      Wt1[(size_t)(n0+ty+i)*D_IN + k0+tx] = f2bf(tile[tx][ty+i]);
  } else {
    int idx = (blockIdx.x - 1024)*256 + threadIdx.x;   // 48*2048, layout [n][k]
    if (idx < 48*D_HID){
      int n = idx >> 11, k = idx & (D_HID-1);
      Wt2[idx] = (n < N_CLS) ? f2bf(W2[k*N_CLS + n]) : (unsigned short)0;
    }
  }
}

// ---------------- propagate(Xb) -> Pb (bf16), one wave per node ----------------
__global__ __launch_bounds__(256) void k_gather1(const unsigned short* __restrict__ Xb,
                          const int* __restrict__ csr_src,
                          const int* __restrict__ offsets, const int* __restrict__ deg,
                          const float* __restrict__ dinv, unsigned short* __restrict__ Pb){
  const int w    = threadIdx.x >> 6;
  const int lane = threadIdx.x & 63;
  const int i    = blockIdx.x*4 + w;       // 2500 blocks x 4 waves
  const float di = dinv[i];
  float acc[8];
  us8 xi = *(const us8*)(Xb + (size_t)i*D_IN + lane*8);
  const float dii = di*di;
  #pragma unroll
  for (int r = 0; r < 8; r++) acc[r] = dii * bf2f(xi[r]);
  const int start = offsets[i], cnt = deg[i];
  for (int c0 = 0; c0 < cnt; c0 += 64){
    int m = cnt - c0; if (m > 64) m = 64;
    int s = 0; float cf = 0.0f;
    if (lane < m){ s = csr_src[start + c0 + lane]; cf = dinv[s]*di; }
    for (int j = 0; j < m; j++){
      int   sj = __shfl(s, j);
      float cj = __shfl(cf, j);
      us8 xr = *(const us8*)(Xb + (size_t)sj*D_IN + lane*8);
      #pragma unroll
      for (int r = 0; r < 8; r++) acc[r] += cj * bf2f(xr[r]);
    }
  }
  us8 o;
  #pragma unroll
  for (int r = 0; r < 8; r++) o[r] = f2bf(acc[r]);
  *(us8*)(Pb + (size_t)i*D_IN + lane*8) = o;
}

// ---------------- GEMM1 v2.1: barrier-free K-loop, fragment-major B ----------------
// Block = 512 rows x 64-col panel. B panel staged ONCE in MFMA-fragment order:
// tile (ks,j) is 1KB where LDS unit `lane` holds lane's b-fragment -> inner
// reads are ds_read_b128 at base+lane*16 (linear, conflict-free). 8 waves run
// private K-loops, A frags global->VGPR with 1-deep prefetch, no barriers.
// grid (20,32): 640 blocks, 64KB LDS -> 2 blocks/CU, 4 waves/SIMD.
__global__ __launch_bounds__(512, 4) void k_gemm1(const unsigned short* __restrict__ Pb,
                                                  const unsigned short* __restrict__ Wt1,
                                                  const float* __restrict__ b1,
                                                  unsigned short* __restrict__ H1){
  __shared__ short Bs[64*512];           // 64 tiles x 1KB
  const int t    = threadIdx.x;
  const int lane = t & 63;
  const int wid  = t >> 6;               // 8 waves
  const int mblk = blockIdx.x;           // 0..19
  const int n0   = blockIdx.y*64;        // 0..31 panels
  // stage: tile id = ks*4+j; wave w stages tiles w*8..w*8+7.
  // source for LDS unit u: row n0+j*16+(u&15), cols ks*32+(u>>4)*8
  {
    const int rsub = lane & 15, csub = (lane >> 4)*8;
    #pragma unroll
    for (int tt = 0; tt < 8; tt++){
      int tile = wid*8 + tt;
      int ks = tile >> 2, j = tile & 3;
      gl_lds16(Wt1 + (size_t)(n0 + j*16 + rsub)*D_IN + ks*32 + csub,
               Bs + tile*512 + lane*8);
    }
  }
  __syncthreads();

  const int fr = lane & 15;
  const int q  = lane >> 4;
  const int mrow0 = mblk*512 + wid*64;
  const unsigned short* Ap = Pb + (size_t)(mrow0 + fr)*D_IN + q*8;
  const short* Bl = Bs + lane*8;

  f32x4 acc[4][4] = {};
  bf16x8 ac[4], an[4];
  #pragma unroll
  for (int i = 0; i < 4; i++) ac[i] = *(const bf16x8*)(Ap + i*16*D_IN);
  for (int ks = 0; ks < 16; ks++){
    if (ks < 15){
      #pragma unroll
      for (int i = 0; i < 4; i++) an[i] = *(const bf16x8*)(Ap + i*16*D_IN + (ks+1)*32);
    }
    #pragma unroll
    for (int j = 0; j < 4; j++){
      bf16x8 b = *(const bf16x8*)(Bl + (ks*4 + j)*512);
      #pragma unroll
      for (int i = 0; i < 4; i++)
        acc[i][j] = __builtin_amdgcn_mfma_f32_16x16x32_bf16(ac[i], b, acc[i][j], 0, 0, 0);
    }
    #pragma unroll
    for (int i = 0; i < 4; i++) ac[i] = an[i];
  }
  // epilogue
  #pragma unroll
  for (int j = 0; j < 4; j++){
    int col = n0 + j*16 + fr;
    float bias = b1[col];
    #pragma unroll
    for (int i = 0; i < 4; i++){
      int rbase = mrow0 + i*16 + q*4;
      f32x4 v = acc[i][j];
      #pragma unroll
      for (int r = 0; r < 4; r++){
        int row = rbase + r;
        if (row < N_NODES){
          float h = fmaxf(v[r] + bias, 0.0f);
          H1[(size_t)row*D_HID + col] = f2bf(h);
        }
      }
    }
  }
}

// ---------------- GEMM2: G = H1 @ W2 (split-K across 4 waves, atomic) ----------------
__global__ __launch_bounds__(256) void k_gemm2(const unsigned short* __restrict__ H1,
                                               const unsigned short* __restrict__ Wt2,
                                               float* __restrict__ G){
  __shared__ short As[4][64*32];
  __shared__ short Bs[4][48*32];
  const int t    = threadIdx.x;
  const int lane = t & 63;
  const int wid  = t >> 6;
  const int m0   = blockIdx.x*64;
  const int lrow = lane >> 2;
  const int lkof = ((lane & 3) ^ ((lane >> 3) & 3))*8;
  const int fr   = lane & 15;
  const int sq8  = ((lane >> 4) ^ ((fr >> 1) & 3))*8;
  const int fq   = lane >> 4;
  f32x4 acc[4][3] = {};
  for (int it = 0; it < 16; it++){
    const int kb = wid*512 + it*32;
    #pragma unroll
    for (int c = 0; c < 4; c++)
      gl_lds16(H1 + (size_t)(m0 + c*16 + lrow)*D_HID + kb + lkof, &As[wid][c*512 + lane*8]);
    #pragma unroll
    for (int c = 0; c < 3; c++)
      gl_lds16(Wt2 + (size_t)(c*16 + lrow)*D_HID + kb + lkof, &Bs[wid][c*512 + lane*8]);
    __syncthreads();
    bf16x8 a[4], b[3];
    #pragma unroll
    for (int i = 0; i < 4; i++) a[i] = *(const bf16x8*)(&As[wid][(i*16 + fr)*32 + sq8]);
    #pragma unroll
    for (int j = 0; j < 3; j++) b[j] = *(const bf16x8*)(&Bs[wid][(j*16 + fr)*32 + sq8]);
    #pragma unroll
    for (int i = 0; i < 4; i++)
      #pragma unroll
      for (int j = 0; j < 3; j++)
        acc[i][j] = __builtin_amdgcn_mfma_f32_16x16x32_bf16(a[i], b[j], acc[i][j], 0, 0, 0);
    __syncthreads();
  }
  #pragma unroll
  for (int j = 0; j < 3; j++){
    int col = j*16 + fr;
    #pragma unroll
    for (int i = 0; i < 4; i++){
      int rbase = m0 + i*16 + fq*4;
      f32x4 v = acc[i][j];
      #pragma unroll
      for (int r = 0; r < 4; r++){
        int row = rbase + r;
        if (row < N_NODES && col < N_CLS)
          atomicAdd(&G[row*N_CLS + col], v[r]);
      }
    }
  }
}

// ---------------- propagate(G) + b2 -> out ----------------
__global__ void k_gather2(const float* __restrict__ G, const int* __restrict__ csr_src,
                          const int* __restrict__ offsets, const int* __restrict__ deg,
                          const float* __restrict__ dinv, const float* __restrict__ b2,
                          float* __restrict__ out){
  __shared__ int   ssrc[64];
  __shared__ float scoef[64];
  const int i = blockIdx.x;
  const int t = threadIdx.x;
  const float di = dinv[i];
  const int start = offsets[i], cnt = deg[i];
  float acc = 0.0f;
  if (t < N_CLS) acc = di*di * G[i*N_CLS + t];
  for (int c0 = 0; c0 < cnt; c0 += 64){
    int m = cnt - c0; if (m > 64) m = 64;
    if (t < m){
      int s = csr_src[start + c0 + t];
      ssrc[t] = s; scoef[t] = dinv[s]*di;
    }
    __syncthreads();
    if (t < N_CLS)
      for (int j = 0; j < m; j++)
        acc += scoef[j] * G[ssrc[j]*N_CLS + t];
    __syncthreads();
  }
  if (t < N_CLS) out[i*N_CLS + t] = acc + b2[t];
}

extern "C" void kernel_launch(void* const* d_in, const int* in_sizes, int n_in,
                              void* d_out, int out_size, void* d_ws, size_t ws_size,
                              hipStream_t stream){
  const float* x  = (const float*)d_in[0];
  const int*   ei = (const int*)d_in[1];
  const float* W1 = (const float*)d_in[2];
  const float* b1 = (const float*)d_in[3];
  const float* W2 = (const float*)d_in[4];
  const float* b2 = (const float*)d_in[5];
  float* out = (float*)d_out;

  char* ws = (char*)d_ws;
  size_t off = 0;
  auto alloc = [&](size_t bytes) -> void* {
    void* p = ws + off; off += (bytes + 255) & ~(size_t)255; return p;
  };
  int*   deg     = (int*)alloc((size_t)N_NODES*4);
  float* dinv    = (float*)alloc((size_t)N_NODES*4);
  int*   offsets = (int*)alloc((size_t)N_NODES*4);
  int*   cursor  = (int*)alloc((size_t)N_NODES*4);
  int*   csr     = (int*)alloc((size_t)N_EDGES*4);
  unsigned short* Xb  = (unsigned short*)alloc((size_t)N_NODES*D_IN*2);
  unsigned short* Pb  = (unsigned short*)alloc((size_t)MP2*D_IN*2);
  unsigned short* Wt1 = (unsigned short*)alloc((size_t)D_HID*D_IN*2);
  unsigned short* Wt2 = (unsigned short*)alloc((size_t)48*D_HID*2);
  unsigned short* H1  = (unsigned short*)alloc((size_t)MP1*D_HID*2);
  float* G = (float*)alloc((size_t)N_NODES*N_CLS*4);

  hipMemsetAsync(deg, 0, (size_t)N_NODES*4, stream);
  hipMemsetAsync(G,   0, (size_t)N_NODES*N_CLS*4, stream);

  k_prep0<<<2500 + 1250, 256, 0, stream>>>(x, Xb, ei, deg);
  k_scan<<<1, 1024, 0, stream>>>(deg, offsets, cursor, dinv);
  k_fill<<<(N_EDGES+255)/256, 256, 0, stream>>>(ei, cursor, csr);
  k_prepW<<<1024 + 384, 256, 0, stream>>>(W1, Wt1, W2, Wt2);
  k_gather1<<<N_NODES/4, 256, 0, stream>>>(Xb, csr, offsets, deg, dinv, Pb);
  k_gemm1<<<dim3(20, 32), 512, 0, stream>>>(Pb, Wt1, b1, H1);
  k_gemm2<<<(N_NODES+63)/64, 256, 0, stream>>>(H1, Wt2, G);
  k_gather2<<<N_NODES, 64, 0, stream>>>(G, csr, offsets, deg, dinv, b2, out);
}

// Round 6
// 253.451 us; speedup vs baseline: 1.3186x; 1.1014x over previous
//
#include <hip/hip_runtime.h>
#include <stdint.h>

#define N_NODES 10000
#define N_EDGES 320000
#define D_IN    512
#define D_HID   2048
#define N_CLS   40
#define MP1     10112   // 79*128 (GEMM1 M padding)
#define HSTR    136     // Hs row stride (shorts): 272B = 16B-aligned, breaks pow2 banks

typedef float f32x4  __attribute__((ext_vector_type(4)));
typedef short bf16x8 __attribute__((ext_vector_type(8)));
typedef unsigned short us8 __attribute__((ext_vector_type(8)));

__device__ inline unsigned short f2bf(float f){
  unsigned int u = __float_as_uint(f);
  u += 0x7fffu + ((u >> 16) & 1u);   // round-to-nearest-even
  return (unsigned short)(u >> 16);
}

__device__ inline float bf2f(unsigned short h){
  return __uint_as_float(((unsigned int)h) << 16);
}

__device__ inline void gl_lds16(const void* g, void* l){
  __builtin_amdgcn_global_load_lds((const __attribute__((address_space(1))) void*)g,
                                   (__attribute__((address_space(3))) void*)l, 16, 0, 0);
}

// ---------------- fused: x->bf16 cast + degree count ----------------
__global__ void k_prep0(const float* __restrict__ x, unsigned short* __restrict__ Xb,
                        const int* __restrict__ ei, int* __restrict__ deg){
  if (blockIdx.x < 2500){
    int idx = blockIdx.x*256 + threadIdx.x;
    const f32x4* x4 = (const f32x4*)x;
    f32x4 a = x4[idx*2], b = x4[idx*2+1];
    us8 o;
    o[0]=f2bf(a.x); o[1]=f2bf(a.y); o[2]=f2bf(a.z); o[3]=f2bf(a.w);
    o[4]=f2bf(b.x); o[5]=f2bf(b.y); o[6]=f2bf(b.z); o[7]=f2bf(b.w);
    *(us8*)(Xb + (size_t)idx*8) = o;
  } else {
    int e = (blockIdx.x - 2500)*256 + threadIdx.x;
    if (e < N_EDGES) atomicAdd(&deg[ei[N_EDGES + e]], 1);
  }
}

__global__ void k_scan(const int* __restrict__ deg, int* __restrict__ offsets,
                       int* __restrict__ cursor, float* __restrict__ dinv){
  __shared__ int sums[1024];
  const int t = threadIdx.x;
  const int CH = 10;
  int base = t*CH;
  int local[CH]; int s = 0;
  for (int j = 0; j < CH; j++){
    int v = (base + j < N_NODES) ? deg[base + j] : 0;
    local[j] = s; s += v;
    if (base + j < N_NODES) dinv[base + j] = rsqrtf((float)v + 1.0f);
  }
  sums[t] = s;
  __syncthreads();
  for (int off = 1; off < 1024; off <<= 1){
    int v = (t >= off) ? sums[t - off] : 0;
    __syncthreads();
    sums[t] += v;
    __syncthreads();
  }
  int pre = (t > 0) ? sums[t-1] : 0;
  for (int j = 0; j < CH; j++){
    int idx = base + j;
    if (idx < N_NODES){ int o = pre + local[j]; offsets[idx] = o; cursor[idx] = o; }
  }
}

__global__ void k_fill(const int* __restrict__ ei, int* __restrict__ cursor, int* __restrict__ csr_src){
  int e = blockIdx.x*256 + threadIdx.x;
  if (e < N_EDGES){
    int s = ei[e], d = ei[N_EDGES + e];
    int pos = atomicAdd(&cursor[d], 1);
    csr_src[pos] = s;
  }
}

// ---------------- fused: gather1 (blocks 0..2499) + weight prep (rest) ----------------
__global__ __launch_bounds__(256) void k_gjoint(const unsigned short* __restrict__ Xb,
                          const int* __restrict__ csr_src,
                          const int* __restrict__ offsets, const int* __restrict__ deg,
                          const float* __restrict__ dinv, unsigned short* __restrict__ Pb,
                          const float* __restrict__ W1, unsigned short* __restrict__ Wt1,
                          const float* __restrict__ W2, unsigned short* __restrict__ Wt2){
  __shared__ float tile[32][33];
  if (blockIdx.x < 2500){
    // propagate(Xb) -> Pb, one wave per node
    const int w    = threadIdx.x >> 6;
    const int lane = threadIdx.x & 63;
    const int i    = blockIdx.x*4 + w;
    const float di = dinv[i];
    float acc[8];
    us8 xi = *(const us8*)(Xb + (size_t)i*D_IN + lane*8);
    const float dii = di*di;
    #pragma unroll
    for (int r = 0; r < 8; r++) acc[r] = dii * bf2f(xi[r]);
    const int start = offsets[i], cnt = deg[i];
    for (int c0 = 0; c0 < cnt; c0 += 64){
      int m = cnt - c0; if (m > 64) m = 64;
      int s = 0; float cf = 0.0f;
      if (lane < m){ s = csr_src[start + c0 + lane]; cf = dinv[s]*di; }
      for (int j = 0; j < m; j++){
        int   sj = __shfl(s, j);
        float cj = __shfl(cf, j);
        us8 xr = *(const us8*)(Xb + (size_t)sj*D_IN + lane*8);
        #pragma unroll
        for (int r = 0; r < 8; r++) acc[r] += cj * bf2f(xr[r]);
      }
    }
    us8 o;
    #pragma unroll
    for (int r = 0; r < 8; r++) o[r] = f2bf(acc[r]);
    *(us8*)(Pb + (size_t)i*D_IN + lane*8) = o;
  } else if (blockIdx.x < 2500 + 1024){
    // W1 [512,2048] -> Wt1 [2048][512] bf16
    const int bb = blockIdx.x - 2500;
    const int n0 = (bb & 63)*32, k0 = (bb >> 6)*32;
    const int tx = threadIdx.x & 31, ty = threadIdx.x >> 5;
    for (int i = 0; i < 32; i += 8)
      tile[ty+i][tx] = W1[(size_t)(k0+ty+i)*D_HID + n0+tx];
    __syncthreads();
    for (int i = 0; i < 32; i += 8)
      Wt1[(size_t)(n0+ty+i)*D_IN + k0+tx] = f2bf(tile[tx][ty+i]);
  } else {
    // W2 [2048,40] -> Wt2 [48][2048] bf16 (zero-padded)
    int idx = (blockIdx.x - 3524)*256 + threadIdx.x;
    if (idx < 48*D_HID){
      int n = idx >> 11, k = idx & (D_HID-1);
      Wt2[idx] = (n < N_CLS) ? f2bf(W2[k*N_CLS + n]) : (unsigned short)0;
    }
  }
}

// ---------------- GEMM1+GEMM2 fused ----------------
// Stage 1 (R3-proven): 128x128 tile, BK=32, global_load_lds w/ XOR swizzle,
// 16x16x32 bf16 MFMA, bias+ReLU. Stage 2: H-tile -> LDS (Hs[128][HSTR]),
// second MFMA vs L2-resident Wt2 (K = this block's 128 h-cols), atomicAdd
// partials into G[10000][40].
__global__ __launch_bounds__(256) void k_gemm1f(const unsigned short* __restrict__ Pb,
                                                const unsigned short* __restrict__ Wt1,
                                                const float* __restrict__ b1,
                                                const unsigned short* __restrict__ Wt2,
                                                float* __restrict__ G){
  __shared__ short smem[128*HSTR];     // 34.8KB; [0,4096) As, [4096,8192) Bs in K-loop
  short* As = smem;
  short* Bs = smem + 4096;
  short* Hs = smem;
  const int t    = threadIdx.x;
  const int lane = t & 63;
  const int wid  = t >> 6;
  const int wm   = (wid >> 1)*64, wn = (wid & 1)*64;
  const int m0   = blockIdx.x*128, n0 = blockIdx.y*128;
  const int arow = t >> 2;
  const int akof = ((t & 3) ^ ((t >> 3) & 3))*8;  // swizzled source chunk
  const int fr   = lane & 15;
  const int q    = lane >> 4;
  const int sq8  = (q ^ ((fr >> 1) & 3))*8;       // swizzled read offset
  f32x4 acc[4][4] = {};
  for (int kb = 0; kb < D_IN; kb += 32){
    gl_lds16(Pb  + (size_t)(m0 +      arow)*D_IN + kb + akof, As + t*8);
    gl_lds16(Pb  + (size_t)(m0 + 64 + arow)*D_IN + kb + akof, As + 2048 + t*8);
    gl_lds16(Wt1 + (size_t)(n0 +      arow)*D_IN + kb + akof, Bs + t*8);
    gl_lds16(Wt1 + (size_t)(n0 + 64 + arow)*D_IN + kb + akof, Bs + 2048 + t*8);
    __syncthreads();
    bf16x8 a[4], b[4];
    #pragma unroll
    for (int i = 0; i < 4; i++) a[i] = *(const bf16x8*)(As + (wm + i*16 + fr)*32 + sq8);
    #pragma unroll
    for (int j = 0; j < 4; j++) b[j] = *(const bf16x8*)(Bs + (wn + j*16 + fr)*32 + sq8);
    #pragma unroll
    for (int i = 0; i < 4; i++)
      #pragma unroll
      for (int j = 0; j < 4; j++)
        acc[i][j] = __builtin_amdgcn_mfma_f32_16x16x32_bf16(a[i], b[j], acc[i][j], 0, 0, 0);
    __syncthreads();
  }
  // epilogue stage A: bias+ReLU, H tile -> LDS bf16
  #pragma unroll
  for (int j = 0; j < 4; j++){
    int col = wn + j*16 + fr;
    float bias = b1[n0 + col];
    #pragma unroll
    for (int i = 0; i < 4; i++){
      int rbase = wm + i*16 + q*4;
      f32x4 v = acc[i][j];
      #pragma unroll
      for (int r = 0; r < 4; r++){
        float h = fmaxf(v[r] + bias, 0.0f);
        Hs[(rbase + r)*HSTR + col] = (short)f2bf(h);
      }
    }
  }
  __syncthreads();
  // epilogue stage B: G_partial = Hs @ Wt2[:, n0:n0+128]^T ; wave owns 32 rows
  f32x4 acc2[2][3] = {};
  for (int ks = 0; ks < 4; ks++){
    bf16x8 a2[2];
    #pragma unroll
    for (int i2 = 0; i2 < 2; i2++)
      a2[i2] = *(const bf16x8*)(Hs + (wid*32 + i2*16 + fr)*HSTR + ks*32 + q*8);
    #pragma unroll
    for (int j2 = 0; j2 < 3; j2++){
      bf16x8 b2 = *(const bf16x8*)(Wt2 + (size_t)(j2*16 + fr)*D_HID + n0 + ks*32 + q*8);
      #pragma unroll
      for (int i2 = 0; i2 < 2; i2++)
        acc2[i2][j2] = __builtin_amdgcn_mfma_f32_16x16x32_bf16(a2[i2], b2, acc2[i2][j2], 0, 0, 0);
    }
  }
  #pragma unroll
  for (int j2 = 0; j2 < 3; j2++){
    int col = j2*16 + fr;
    if (col < N_CLS){
      #pragma unroll
      for (int i2 = 0; i2 < 2; i2++){
        int rbase = m0 + wid*32 + i2*16 + q*4;
        f32x4 v = acc2[i2][j2];
        #pragma unroll
        for (int r = 0; r < 4; r++){
          int row = rbase + r;
          if (row < N_NODES)
            atomicAdd(&G[row*N_CLS + col], v[r]);
        }
      }
    }
  }
}

// ---------------- propagate(G) + b2 -> out ----------------
__global__ void k_gather2(const float* __restrict__ G, const int* __restrict__ csr_src,
                          const int* __restrict__ offsets, const int* __restrict__ deg,
                          const float* __restrict__ dinv, const float* __restrict__ b2,
                          float* __restrict__ out){
  __shared__ int   ssrc[64];
  __shared__ float scoef[64];
  const int i = blockIdx.x;
  const int t = threadIdx.x;
  const float di = dinv[i];
  const int start = offsets[i], cnt = deg[i];
  float acc = 0.0f;
  if (t < N_CLS) acc = di*di * G[i*N_CLS + t];
  for (int c0 = 0; c0 < cnt; c0 += 64){
    int m = cnt - c0; if (m > 64) m = 64;
    if (t < m){
      int s = csr_src[start + c0 + t];
      ssrc[t] = s; scoef[t] = dinv[s]*di;
    }
    __syncthreads();
    if (t < N_CLS)
      for (int j = 0; j < m; j++)
        acc += scoef[j] * G[ssrc[j]*N_CLS + t];
    __syncthreads();
  }
  if (t < N_CLS) out[i*N_CLS + t] = acc + b2[t];
}

extern "C" void kernel_launch(void* const* d_in, const int* in_sizes, int n_in,
                              void* d_out, int out_size, void* d_ws, size_t ws_size,
                              hipStream_t stream){
  const float* x  = (const float*)d_in[0];
  const int*   ei = (const int*)d_in[1];
  const float* W1 = (const float*)d_in[2];
  const float* b1 = (const float*)d_in[3];
  const float* W2 = (const float*)d_in[4];
  const float* b2 = (const float*)d_in[5];
  float* out = (float*)d_out;

  char* ws = (char*)d_ws;
  size_t off = 0;
  auto alloc = [&](size_t bytes) -> void* {
    void* p = ws + off; off += (bytes + 255) & ~(size_t)255; return p;
  };
  int*   deg     = (int*)alloc((size_t)N_NODES*4);
  float* dinv    = (float*)alloc((size_t)N_NODES*4);
  int*   offsets = (int*)alloc((size_t)N_NODES*4);
  int*   cursor  = (int*)alloc((size_t)N_NODES*4);
  int*   csr     = (int*)alloc((size_t)N_EDGES*4);
  unsigned short* Xb  = (unsigned short*)alloc((size_t)N_NODES*D_IN*2);
  unsigned short* Pb  = (unsigned short*)alloc((size_t)MP1*D_IN*2);
  unsigned short* Wt1 = (unsigned short*)alloc((size_t)D_HID*D_IN*2);
  unsigned short* Wt2 = (unsigned short*)alloc((size_t)48*D_HID*2);
  float* G = (float*)alloc((size_t)N_NODES*N_CLS*4);

  hipMemsetAsync(deg, 0, (size_t)N_NODES*4, stream);
  hipMemsetAsync(G,   0, (size_t)N_NODES*N_CLS*4, stream);

  k_prep0<<<2500 + 1250, 256, 0, stream>>>(x, Xb, ei, deg);
  k_scan<<<1, 1024, 0, stream>>>(deg, offsets, cursor, dinv);
  k_fill<<<(N_EDGES+255)/256, 256, 0, stream>>>(ei, cursor, csr);
  k_gjoint<<<2500 + 1024 + 384, 256, 0, stream>>>(Xb, csr, offsets, deg, dinv, Pb,
                                                  W1, Wt1, W2, Wt2);
  k_gemm1f<<<dim3(MP1/128, D_IN*4/128), 256, 0, stream>>>(Pb, Wt1, b1, Wt2, G);
  k_gather2<<<N_NODES, 64, 0, stream>>>(G, csr, offsets, deg, dinv, b2, out);
}

// Round 7
// 242.031 us; speedup vs baseline: 1.3808x; 1.0472x over previous
//
#include <hip/hip_runtime.h>
#include <stdint.h>

#define N_NODES 10000
#define N_EDGES 320000
#define D_IN    512
#define D_HID   2048
#define N_CLS   40
#define MP1     10112   // 79*128 (GEMM1 M padding)
#define HSTR    136     // Hs row stride (shorts): 272B, breaks pow2 banks

typedef float f32x4  __attribute__((ext_vector_type(4)));
typedef short bf16x8 __attribute__((ext_vector_type(8)));
typedef unsigned short us8 __attribute__((ext_vector_type(8)));

__device__ inline unsigned short f2bf(float f){
  unsigned int u = __float_as_uint(f);
  u += 0x7fffu + ((u >> 16) & 1u);   // round-to-nearest-even
  return (unsigned short)(u >> 16);
}

__device__ inline float bf2f(unsigned short h){
  return __uint_as_float(((unsigned int)h) << 16);
}

__device__ inline void gl_lds16(const void* g, void* l){
  __builtin_amdgcn_global_load_lds((const __attribute__((address_space(1))) void*)g,
                                   (__attribute__((address_space(3))) void*)l, 16, 0, 0);
}

// ---------------- fused: x->bf16 cast + degree count ----------------
__global__ void k_prep0(const float* __restrict__ x, unsigned short* __restrict__ Xb,
                        const int* __restrict__ ei, int* __restrict__ deg){
  if (blockIdx.x < 2500){
    int idx = blockIdx.x*256 + threadIdx.x;
    const f32x4* x4 = (const f32x4*)x;
    f32x4 a = x4[idx*2], b = x4[idx*2+1];
    us8 o;
    o[0]=f2bf(a.x); o[1]=f2bf(a.y); o[2]=f2bf(a.z); o[3]=f2bf(a.w);
    o[4]=f2bf(b.x); o[5]=f2bf(b.y); o[6]=f2bf(b.z); o[7]=f2bf(b.w);
    *(us8*)(Xb + (size_t)idx*8) = o;
  } else {
    int e = (blockIdx.x - 2500)*256 + threadIdx.x;
    if (e < N_EDGES) atomicAdd(&deg[ei[N_EDGES + e]], 1);
  }
}

__global__ void k_scan(const int* __restrict__ deg, int* __restrict__ offsets,
                       int* __restrict__ cursor, float* __restrict__ dinv){
  __shared__ int sums[1024];
  const int t = threadIdx.x;
  const int CH = 10;
  int base = t*CH;
  int local[CH]; int s = 0;
  for (int j = 0; j < CH; j++){
    int v = (base + j < N_NODES) ? deg[base + j] : 0;
    local[j] = s; s += v;
    if (base + j < N_NODES) dinv[base + j] = rsqrtf((float)v + 1.0f);
  }
  sums[t] = s;
  __syncthreads();
  for (int off = 1; off < 1024; off <<= 1){
    int v = (t >= off) ? sums[t - off] : 0;
    __syncthreads();
    sums[t] += v;
    __syncthreads();
  }
  int pre = (t > 0) ? sums[t-1] : 0;
  for (int j = 0; j < CH; j++){
    int idx = base + j;
    if (idx < N_NODES){ int o = pre + local[j]; offsets[idx] = o; cursor[idx] = o; }
  }
}

__global__ void k_fill(const int* __restrict__ ei, int* __restrict__ cursor, int* __restrict__ csr_src){
  int e = blockIdx.x*256 + threadIdx.x;
  if (e < N_EDGES){
    int s = ei[e], d = ei[N_EDGES + e];
    int pos = atomicAdd(&cursor[d], 1);
    csr_src[pos] = s;
  }
}

// ---------------- fused: gather1 (blocks 0..2499) + weight prep (rest) ----------------
__global__ __launch_bounds__(256) void k_gjoint(const unsigned short* __restrict__ Xb,
                          const int* __restrict__ csr_src,
                          const int* __restrict__ offsets, const int* __restrict__ deg,
                          const float* __restrict__ dinv, unsigned short* __restrict__ Pb,
                          const float* __restrict__ W1, unsigned short* __restrict__ Wt1,
                          const float* __restrict__ W2, unsigned short* __restrict__ Wt2){
  __shared__ float tile[32][33];
  if (blockIdx.x < 2500){
    const int w    = threadIdx.x >> 6;
    const int lane = threadIdx.x & 63;
    const int i    = blockIdx.x*4 + w;
    const float di = dinv[i];
    float acc[8];
    us8 xi = *(const us8*)(Xb + (size_t)i*D_IN + lane*8);
    const float dii = di*di;
    #pragma unroll
    for (int r = 0; r < 8; r++) acc[r] = dii * bf2f(xi[r]);
    const int start = offsets[i], cnt = deg[i];
    for (int c0 = 0; c0 < cnt; c0 += 64){
      int m = cnt - c0; if (m > 64) m = 64;
      int s = 0; float cf = 0.0f;
      if (lane < m){ s = csr_src[start + c0 + lane]; cf = dinv[s]*di; }
      for (int j = 0; j < m; j++){
        int   sj = __shfl(s, j);
        float cj = __shfl(cf, j);
        us8 xr = *(const us8*)(Xb + (size_t)sj*D_IN + lane*8);
        #pragma unroll
        for (int r = 0; r < 8; r++) acc[r] += cj * bf2f(xr[r]);
      }
    }
    us8 o;
    #pragma unroll
    for (int r = 0; r < 8; r++) o[r] = f2bf(acc[r]);
    *(us8*)(Pb + (size_t)i*D_IN + lane*8) = o;
  } else if (blockIdx.x < 2500 + 1024){
    const int bb = blockIdx.x - 2500;
    const int n0 = (bb & 63)*32, k0 = (bb >> 6)*32;
    const int tx = threadIdx.x & 31, ty = threadIdx.x >> 5;
    for (int i = 0; i < 32; i += 8)
      tile[ty+i][tx] = W1[(size_t)(k0+ty+i)*D_HID + n0+tx];
    __syncthreads();
    for (int i = 0; i < 32; i += 8)
      Wt1[(size_t)(n0+ty+i)*D_IN + k0+tx] = f2bf(tile[tx][ty+i]);
  } else {
    int idx = (blockIdx.x - 3524)*256 + threadIdx.x;
    if (idx < 48*D_HID){
      int n = idx >> 11, k = idx & (D_HID-1);
      Wt2[idx] = (n < N_CLS) ? f2bf(W2[k*N_CLS + n]) : (unsigned short)0;
    }
  }
}

// ---------------- GEMM1+GEMM2 fused, double-buffered K-loop ----------------
// dbuf: buf p = smem[p*8192 .. p*8192+8192) (As 4096 + Bs 4096 shorts).
// Per iter: issue next-iter global_load_lds into alt buffer, then raw
// s_waitcnt vmcnt(4) (only current buffer's 4 loads) + s_barrier -- never a
// full vmcnt(0) drain except the peeled last iter. Hs (epilogue) unions smem.
__global__ __launch_bounds__(256) void k_gemm1f(const unsigned short* __restrict__ Pb,
                                                const unsigned short* __restrict__ Wt1,
                                                const float* __restrict__ b1,
                                                const unsigned short* __restrict__ Wt2,
                                                float* __restrict__ G){
  __shared__ short smem[128*HSTR];     // 34816 B; K-loop uses [0,32KB) as 2 bufs
  short* Hs = smem;
  const int t    = threadIdx.x;
  const int lane = t & 63;
  const int wid  = t >> 6;
  const int wm   = (wid >> 1)*64, wn = (wid & 1)*64;
  const int m0   = blockIdx.x*128, n0 = blockIdx.y*128;
  const int arow = t >> 2;
  const int akof = ((t & 3) ^ ((t >> 3) & 3))*8;  // swizzled source chunk
  const int fr   = lane & 15;
  const int q    = lane >> 4;
  const int sq8  = (q ^ ((fr >> 1) & 3))*8;       // swizzled read offset

  const unsigned short* ApA = Pb  + (size_t)(m0 +      arow)*D_IN + akof;
  const unsigned short* ApB = Pb  + (size_t)(m0 + 64 + arow)*D_IN + akof;
  const unsigned short* BpA = Wt1 + (size_t)(n0 +      arow)*D_IN + akof;
  const unsigned short* BpB = Wt1 + (size_t)(n0 + 64 + arow)*D_IN + akof;

  f32x4 acc[4][4] = {};
  // prologue: stage iter 0 into buf 0
  {
    short* As = smem;       short* Bs = smem + 4096;
    gl_lds16(ApA, As + t*8);  gl_lds16(ApB, As + 2048 + t*8);
    gl_lds16(BpA, Bs + t*8);  gl_lds16(BpB, Bs + 2048 + t*8);
  }
  #pragma unroll
  for (int ks = 0; ks < 16; ks++){
    if (ks < 15){
      short* As = smem + ((ks+1)&1)*8192;
      short* Bs = As + 4096;
      const int kb = (ks+1)*32;
      gl_lds16(ApA + kb, As + t*8);  gl_lds16(ApB + kb, As + 2048 + t*8);
      gl_lds16(BpA + kb, Bs + t*8);  gl_lds16(BpB + kb, Bs + 2048 + t*8);
      asm volatile("" ::: "memory");
      __builtin_amdgcn_s_waitcnt(0x0F74);   // vmcnt(4): current buf done, next in flight
    } else {
      asm volatile("" ::: "memory");
      __builtin_amdgcn_s_waitcnt(0x0F70);   // vmcnt(0): last buf
    }
    __builtin_amdgcn_s_barrier();
    asm volatile("" ::: "memory");
    const short* As = smem + (ks&1)*8192;
    const short* Bs = As + 4096;
    bf16x8 a[4], b[4];
    #pragma unroll
    for (int i = 0; i < 4; i++) a[i] = *(const bf16x8*)(As + (wm + i*16 + fr)*32 + sq8);
    #pragma unroll
    for (int j = 0; j < 4; j++) b[j] = *(const bf16x8*)(Bs + (wn + j*16 + fr)*32 + sq8);
    #pragma unroll
    for (int i = 0; i < 4; i++)
      #pragma unroll
      for (int j = 0; j < 4; j++)
        acc[i][j] = __builtin_amdgcn_mfma_f32_16x16x32_bf16(a[i], b[j], acc[i][j], 0, 0, 0);
    asm volatile("" ::: "memory");
    __builtin_amdgcn_s_barrier();           // reads of this buf done before overwrite
    asm volatile("" ::: "memory");
  }
  // epilogue stage A: bias+ReLU, H tile -> LDS bf16
  #pragma unroll
  for (int j = 0; j < 4; j++){
    int col = wn + j*16 + fr;
    float bias = b1[n0 + col];
    #pragma unroll
    for (int i = 0; i < 4; i++){
      int rbase = wm + i*16 + q*4;
      f32x4 v = acc[i][j];
      #pragma unroll
      for (int r = 0; r < 4; r++){
        float h = fmaxf(v[r] + bias, 0.0f);
        Hs[(rbase + r)*HSTR + col] = (short)f2bf(h);
      }
    }
  }
  __syncthreads();
  // epilogue stage B: G_partial = Hs @ Wt2[:, n0:n0+128]^T ; wave owns 32 rows
  f32x4 acc2[2][3] = {};
  for (int ks = 0; ks < 4; ks++){
    bf16x8 a2[2];
    #pragma unroll
    for (int i2 = 0; i2 < 2; i2++)
      a2[i2] = *(const bf16x8*)(Hs + (wid*32 + i2*16 + fr)*HSTR + ks*32 + q*8);
    #pragma unroll
    for (int j2 = 0; j2 < 3; j2++){
      bf16x8 b2 = *(const bf16x8*)(Wt2 + (size_t)(j2*16 + fr)*D_HID + n0 + ks*32 + q*8);
      #pragma unroll
      for (int i2 = 0; i2 < 2; i2++)
        acc2[i2][j2] = __builtin_amdgcn_mfma_f32_16x16x32_bf16(a2[i2], b2, acc2[i2][j2], 0, 0, 0);
    }
  }
  #pragma unroll
  for (int j2 = 0; j2 < 3; j2++){
    int col = j2*16 + fr;
    if (col < N_CLS){
      #pragma unroll
      for (int i2 = 0; i2 < 2; i2++){
        int rbase = m0 + wid*32 + i2*16 + q*4;
        f32x4 v = acc2[i2][j2];
        #pragma unroll
        for (int r = 0; r < 4; r++){
          int row = rbase + r;
          if (row < N_NODES)
            atomicAdd(&G[row*N_CLS + col], v[r]);
        }
      }
    }
  }
}

// ---------------- propagate(G) + b2 -> out ----------------
__global__ void k_gather2(const float* __restrict__ G, const int* __restrict__ csr_src,
                          const int* __restrict__ offsets, const int* __restrict__ deg,
                          const float* __restrict__ dinv, const float* __restrict__ b2,
                          float* __restrict__ out){
  __shared__ int   ssrc[64];
  __shared__ float scoef[64];
  const int i = blockIdx.x;
  const int t = threadIdx.x;
  const float di = dinv[i];
  const int start = offsets[i], cnt = deg[i];
  float acc = 0.0f;
  if (t < N_CLS) acc = di*di * G[i*N_CLS + t];
  for (int c0 = 0; c0 < cnt; c0 += 64){
    int m = cnt - c0; if (m > 64) m = 64;
    if (t < m){
      int s = csr_src[start + c0 + t];
      ssrc[t] = s; scoef[t] = dinv[s]*di;
    }
    __syncthreads();
    if (t < N_CLS)
      for (int j = 0; j < m; j++)
        acc += scoef[j] * G[ssrc[j]*N_CLS + t];
    __syncthreads();
  }
  if (t < N_CLS) out[i*N_CLS + t] = acc + b2[t];
}

extern "C" void kernel_launch(void* const* d_in, const int* in_sizes, int n_in,
                              void* d_out, int out_size, void* d_ws, size_t ws_size,
                              hipStream_t stream){
  const float* x  = (const float*)d_in[0];
  const int*   ei = (const int*)d_in[1];
  const float* W1 = (const float*)d_in[2];
  const float* b1 = (const float*)d_in[3];
  const float* W2 = (const float*)d_in[4];
  const float* b2 = (const float*)d_in[5];
  float* out = (float*)d_out;

  char* ws = (char*)d_ws;
  size_t off = 0;
  auto alloc = [&](size_t bytes) -> void* {
    void* p = ws + off; off += (bytes + 255) & ~(size_t)255; return p;
  };
  int*   deg     = (int*)alloc((size_t)N_NODES*4);
  float* dinv    = (float*)alloc((size_t)N_NODES*4);
  int*   offsets = (int*)alloc((size_t)N_NODES*4);
  int*   cursor  = (int*)alloc((size_t)N_NODES*4);
  int*   csr     = (int*)alloc((size_t)N_EDGES*4);
  unsigned short* Xb  = (unsigned short*)alloc((size_t)N_NODES*D_IN*2);
  unsigned short* Pb  = (unsigned short*)alloc((size_t)MP1*D_IN*2);
  unsigned short* Wt1 = (unsigned short*)alloc((size_t)D_HID*D_IN*2);
  unsigned short* Wt2 = (unsigned short*)alloc((size_t)48*D_HID*2);
  float* G = (float*)alloc((size_t)N_NODES*N_CLS*4);

  hipMemsetAsync(deg, 0, (size_t)N_NODES*4, stream);
  hipMemsetAsync(G,   0, (size_t)N_NODES*N_CLS*4, stream);

  k_prep0<<<2500 + 1250, 256, 0, stream>>>(x, Xb, ei, deg);
  k_scan<<<1, 1024, 0, stream>>>(deg, offsets, cursor, dinv);
  k_fill<<<(N_EDGES+255)/256, 256, 0, stream>>>(ei, cursor, csr);
  k_gjoint<<<2500 + 1024 + 384, 256, 0, stream>>>(Xb, csr, offsets, deg, dinv, Pb,
                                                  W1, Wt1, W2, Wt2);
  k_gemm1f<<<dim3(MP1/128, D_IN*4/128), 256, 0, stream>>>(Pb, Wt1, b1, Wt2, G);
  k_gather2<<<N_NODES, 64, 0, stream>>>(G, csr, offsets, deg, dinv, b2, out);
}

// Round 8
// 241.587 us; speedup vs baseline: 1.3833x; 1.0018x over previous
//
#include <hip/hip_runtime.h>
#include <stdint.h>

#define N_NODES 10000
#define N_EDGES 320000
#define D_IN    512
#define D_HID   2048
#define N_CLS   40
#define MP1     10112   // 79*128 (GEMM1 M padding)
#define HSTR    136     // Hs row stride (shorts): 272B, breaks pow2 banks

typedef float f32x4  __attribute__((ext_vector_type(4)));
typedef short bf16x8 __attribute__((ext_vector_type(8)));
typedef unsigned short us8 __attribute__((ext_vector_type(8)));

__device__ inline unsigned short f2bf(float f){
  unsigned int u = __float_as_uint(f);
  u += 0x7fffu + ((u >> 16) & 1u);   // round-to-nearest-even
  return (unsigned short)(u >> 16);
}

__device__ inline float bf2f(unsigned short h){
  return __uint_as_float(((unsigned int)h) << 16);
}

__device__ inline void gl_lds16(const void* g, void* l){
  __builtin_amdgcn_global_load_lds((const __attribute__((address_space(1))) void*)g,
                                   (__attribute__((address_space(3))) void*)l, 16, 0, 0);
}

// ---------------- fused: x->bf16 cast + degree count ----------------
__global__ void k_prep0(const float* __restrict__ x, unsigned short* __restrict__ Xb,
                        const int* __restrict__ ei, int* __restrict__ deg){
  if (blockIdx.x < 2500){
    int idx = blockIdx.x*256 + threadIdx.x;
    const f32x4* x4 = (const f32x4*)x;
    f32x4 a = x4[idx*2], b = x4[idx*2+1];
    us8 o;
    o[0]=f2bf(a.x); o[1]=f2bf(a.y); o[2]=f2bf(a.z); o[3]=f2bf(a.w);
    o[4]=f2bf(b.x); o[5]=f2bf(b.y); o[6]=f2bf(b.z); o[7]=f2bf(b.w);
    *(us8*)(Xb + (size_t)idx*8) = o;
  } else {
    int e = (blockIdx.x - 2500)*256 + threadIdx.x;
    if (e < N_EDGES) atomicAdd(&deg[ei[N_EDGES + e]], 1);
  }
}

__global__ void k_scan(const int* __restrict__ deg, int* __restrict__ offsets,
                       int* __restrict__ cursor, float* __restrict__ dinv){
  __shared__ int sums[1024];
  const int t = threadIdx.x;
  const int CH = 10;
  int base = t*CH;
  int local[CH]; int s = 0;
  for (int j = 0; j < CH; j++){
    int v = (base + j < N_NODES) ? deg[base + j] : 0;
    local[j] = s; s += v;
    if (base + j < N_NODES) dinv[base + j] = rsqrtf((float)v + 1.0f);
  }
  sums[t] = s;
  __syncthreads();
  for (int off = 1; off < 1024; off <<= 1){
    int v = (t >= off) ? sums[t - off] : 0;
    __syncthreads();
    sums[t] += v;
    __syncthreads();
  }
  int pre = (t > 0) ? sums[t-1] : 0;
  for (int j = 0; j < CH; j++){
    int idx = base + j;
    if (idx < N_NODES){ int o = pre + local[j]; offsets[idx] = o; cursor[idx] = o; }
  }
}

__global__ void k_fill(const int* __restrict__ ei, int* __restrict__ cursor, int* __restrict__ csr_src){
  int e = blockIdx.x*256 + threadIdx.x;
  if (e < N_EDGES){
    int s = ei[e], d = ei[N_EDGES + e];
    int pos = atomicAdd(&cursor[d], 1);
    csr_src[pos] = s;
  }
}

// ---------------- fused: gather1 (blocks 0..2499) + weight prep (rest) ----------------
__global__ __launch_bounds__(256) void k_gjoint(const unsigned short* __restrict__ Xb,
                          const int* __restrict__ csr_src,
                          const int* __restrict__ offsets, const int* __restrict__ deg,
                          const float* __restrict__ dinv, unsigned short* __restrict__ Pb,
                          const float* __restrict__ W1, unsigned short* __restrict__ Wt1,
                          const float* __restrict__ W2, unsigned short* __restrict__ Wt2){
  __shared__ float tile[32][33];
  if (blockIdx.x < 2500){
    const int w    = threadIdx.x >> 6;
    const int lane = threadIdx.x & 63;
    const int i    = blockIdx.x*4 + w;
    const float di = dinv[i];
    float acc[8];
    us8 xi = *(const us8*)(Xb + (size_t)i*D_IN + lane*8);
    const float dii = di*di;
    #pragma unroll
    for (int r = 0; r < 8; r++) acc[r] = dii * bf2f(xi[r]);
    const int start = offsets[i], cnt = deg[i];
    for (int c0 = 0; c0 < cnt; c0 += 64){
      int m = cnt - c0; if (m > 64) m = 64;
      int s = 0; float cf = 0.0f;
      if (lane < m){ s = csr_src[start + c0 + lane]; cf = dinv[s]*di; }
      for (int j = 0; j < m; j++){
        int   sj = __shfl(s, j);
        float cj = __shfl(cf, j);
        us8 xr = *(const us8*)(Xb + (size_t)sj*D_IN + lane*8);
        #pragma unroll
        for (int r = 0; r < 8; r++) acc[r] += cj * bf2f(xr[r]);
      }
    }
    us8 o;
    #pragma unroll
    for (int r = 0; r < 8; r++) o[r] = f2bf(acc[r]);
    *(us8*)(Pb + (size_t)i*D_IN + lane*8) = o;
  } else if (blockIdx.x < 2500 + 1024){
    const int bb = blockIdx.x - 2500;
    const int n0 = (bb & 63)*32, k0 = (bb >> 6)*32;
    const int tx = threadIdx.x & 31, ty = threadIdx.x >> 5;
    for (int i = 0; i < 32; i += 8)
      tile[ty+i][tx] = W1[(size_t)(k0+ty+i)*D_HID + n0+tx];
    __syncthreads();
    for (int i = 0; i < 32; i += 8)
      Wt1[(size_t)(n0+ty+i)*D_IN + k0+tx] = f2bf(tile[tx][ty+i]);
  } else {
    int idx = (blockIdx.x - 3524)*256 + threadIdx.x;
    if (idx < 48*D_HID){
      int n = idx >> 11, k = idx & (D_HID-1);
      Wt2[idx] = (n < N_CLS) ? f2bf(W2[k*N_CLS + n]) : (unsigned short)0;
    }
  }
}

// ---------------- GEMM1+GEMM2 fused, double-buffered K-loop ----------------
// Grid (16 n-panels, 79 m-tiles), bx = n-panel FAST: the ~64 co-resident
// blocks per XCD then cover all 16 B panels (2MB, L2-pinned) x ~4 m-tiles
// (512KB streaming) -> staging loads are L2 hits, so the 1-deep dbuf
// (s_waitcnt vmcnt(4), never 0 mid-loop) fully hides them.
__global__ __launch_bounds__(256) void k_gemm1f(const unsigned short* __restrict__ Pb,
                                                const unsigned short* __restrict__ Wt1,
                                                const float* __restrict__ b1,
                                                const unsigned short* __restrict__ Wt2,
                                                float* __restrict__ G){
  __shared__ short smem[128*HSTR];     // 34816 B; K-loop uses [0,32KB) as 2 bufs
  short* Hs = smem;
  const int t    = threadIdx.x;
  const int lane = t & 63;
  const int wid  = t >> 6;
  const int wm   = (wid >> 1)*64, wn = (wid & 1)*64;
  const int m0   = blockIdx.y*128, n0 = blockIdx.x*128;   // SWAPPED vs R7
  const int arow = t >> 2;
  const int akof = ((t & 3) ^ ((t >> 3) & 3))*8;  // swizzled source chunk
  const int fr   = lane & 15;
  const int q    = lane >> 4;
  const int sq8  = (q ^ ((fr >> 1) & 3))*8;       // swizzled read offset

  const unsigned short* ApA = Pb  + (size_t)(m0 +      arow)*D_IN + akof;
  const unsigned short* ApB = Pb  + (size_t)(m0 + 64 + arow)*D_IN + akof;
  const unsigned short* BpA = Wt1 + (size_t)(n0 +      arow)*D_IN + akof;
  const unsigned short* BpB = Wt1 + (size_t)(n0 + 64 + arow)*D_IN + akof;

  f32x4 acc[4][4] = {};
  // prologue: stage iter 0 into buf 0
  {
    short* As = smem;       short* Bs = smem + 4096;
    gl_lds16(ApA, As + t*8);  gl_lds16(ApB, As + 2048 + t*8);
    gl_lds16(BpA, Bs + t*8);  gl_lds16(BpB, Bs + 2048 + t*8);
  }
  #pragma unroll
  for (int ks = 0; ks < 16; ks++){
    if (ks < 15){
      short* As = smem + ((ks+1)&1)*8192;
      short* Bs = As + 4096;
      const int kb = (ks+1)*32;
      gl_lds16(ApA + kb, As + t*8);  gl_lds16(ApB + kb, As + 2048 + t*8);
      gl_lds16(BpA + kb, Bs + t*8);  gl_lds16(BpB + kb, Bs + 2048 + t*8);
      asm volatile("" ::: "memory");
      __builtin_amdgcn_s_waitcnt(0x0F74);   // vmcnt(4): current buf done, next in flight
    } else {
      asm volatile("" ::: "memory");
      __builtin_amdgcn_s_waitcnt(0x0F70);   // vmcnt(0): last buf
    }
    __builtin_amdgcn_s_barrier();
    asm volatile("" ::: "memory");
    const short* As = smem + (ks&1)*8192;
    const short* Bs = As + 4096;
    bf16x8 a[4], b[4];
    #pragma unroll
    for (int i = 0; i < 4; i++) a[i] = *(const bf16x8*)(As + (wm + i*16 + fr)*32 + sq8);
    #pragma unroll
    for (int j = 0; j < 4; j++) b[j] = *(const bf16x8*)(Bs + (wn + j*16 + fr)*32 + sq8);
    #pragma unroll
    for (int i = 0; i < 4; i++)
      #pragma unroll
      for (int j = 0; j < 4; j++)
        acc[i][j] = __builtin_amdgcn_mfma_f32_16x16x32_bf16(a[i], b[j], acc[i][j], 0, 0, 0);
    asm volatile("" ::: "memory");
    __builtin_amdgcn_s_barrier();           // reads of this buf done before overwrite
    asm volatile("" ::: "memory");
  }
  // epilogue stage A: bias+ReLU, H tile -> LDS bf16
  #pragma unroll
  for (int j = 0; j < 4; j++){
    int col = wn + j*16 + fr;
    float bias = b1[n0 + col];
    #pragma unroll
    for (int i = 0; i < 4; i++){
      int rbase = wm + i*16 + q*4;
      f32x4 v = acc[i][j];
      #pragma unroll
      for (int r = 0; r < 4; r++){
        float h = fmaxf(v[r] + bias, 0.0f);
        Hs[(rbase + r)*HSTR + col] = (short)f2bf(h);
      }
    }
  }
  __syncthreads();
  // epilogue stage B: G_partial = Hs @ Wt2[:, n0:n0+128]^T ; wave owns 32 rows
  f32x4 acc2[2][3] = {};
  for (int ks = 0; ks < 4; ks++){
    bf16x8 a2[2];
    #pragma unroll
    for (int i2 = 0; i2 < 2; i2++)
      a2[i2] = *(const bf16x8*)(Hs + (wid*32 + i2*16 + fr)*HSTR + ks*32 + q*8);
    #pragma unroll
    for (int j2 = 0; j2 < 3; j2++){
      bf16x8 b2 = *(const bf16x8*)(Wt2 + (size_t)(j2*16 + fr)*D_HID + n0 + ks*32 + q*8);
      #pragma unroll
      for (int i2 = 0; i2 < 2; i2++)
        acc2[i2][j2] = __builtin_amdgcn_mfma_f32_16x16x32_bf16(a2[i2], b2, acc2[i2][j2], 0, 0, 0);
    }
  }
  #pragma unroll
  for (int j2 = 0; j2 < 3; j2++){
    int col = j2*16 + fr;
    if (col < N_CLS){
      #pragma unroll
      for (int i2 = 0; i2 < 2; i2++){
        int rbase = m0 + wid*32 + i2*16 + q*4;
        f32x4 v = acc2[i2][j2];
        #pragma unroll
        for (int r = 0; r < 4; r++){
          int row = rbase + r;
          if (row < N_NODES)
            atomicAdd(&G[row*N_CLS + col], v[r]);
        }
      }
    }
  }
}

// ---------------- propagate(G) + b2 -> out ----------------
__global__ void k_gather2(const float* __restrict__ G, const int* __restrict__ csr_src,
                          const int* __restrict__ offsets, const int* __restrict__ deg,
                          const float* __restrict__ dinv, const float* __restrict__ b2,
                          float* __restrict__ out){
  __shared__ int   ssrc[64];
  __shared__ float scoef[64];
  const int i = blockIdx.x;
  const int t = threadIdx.x;
  const float di = dinv[i];
  const int start = offsets[i], cnt = deg[i];
  float acc = 0.0f;
  if (t < N_CLS) acc = di*di * G[i*N_CLS + t];
  for (int c0 = 0; c0 < cnt; c0 += 64){
    int m = cnt - c0; if (m > 64) m = 64;
    if (t < m){
      int s = csr_src[start + c0 + t];
      ssrc[t] = s; scoef[t] = dinv[s]*di;
    }
    __syncthreads();
    if (t < N_CLS)
      for (int j = 0; j < m; j++)
        acc += scoef[j] * G[ssrc[j]*N_CLS + t];
    __syncthreads();
  }
  if (t < N_CLS) out[i*N_CLS + t] = acc + b2[t];
}

extern "C" void kernel_launch(void* const* d_in, const int* in_sizes, int n_in,
                              void* d_out, int out_size, void* d_ws, size_t ws_size,
                              hipStream_t stream){
  const float* x  = (const float*)d_in[0];
  const int*   ei = (const int*)d_in[1];
  const float* W1 = (const float*)d_in[2];
  const float* b1 = (const float*)d_in[3];
  const float* W2 = (const float*)d_in[4];
  const float* b2 = (const float*)d_in[5];
  float* out = (float*)d_out;

  char* ws = (char*)d_ws;
  size_t off = 0;
  auto alloc = [&](size_t bytes) -> void* {
    void* p = ws + off; off += (bytes + 255) & ~(size_t)255; return p;
  };
  int*   deg     = (int*)alloc((size_t)N_NODES*4);
  float* dinv    = (float*)alloc((size_t)N_NODES*4);
  int*   offsets = (int*)alloc((size_t)N_NODES*4);
  int*   cursor  = (int*)alloc((size_t)N_NODES*4);
  int*   csr     = (int*)alloc((size_t)N_EDGES*4);
  unsigned short* Xb  = (unsigned short*)alloc((size_t)N_NODES*D_IN*2);
  unsigned short* Pb  = (unsigned short*)alloc((size_t)MP1*D_IN*2);
  unsigned short* Wt1 = (unsigned short*)alloc((size_t)D_HID*D_IN*2);
  unsigned short* Wt2 = (unsigned short*)alloc((size_t)48*D_HID*2);
  float* G = (float*)alloc((size_t)N_NODES*N_CLS*4);

  hipMemsetAsync(deg, 0, (size_t)N_NODES*4, stream);
  hipMemsetAsync(G,   0, (size_t)N_NODES*N_CLS*4, stream);

  k_prep0<<<2500 + 1250, 256, 0, stream>>>(x, Xb, ei, deg);
  k_scan<<<1, 1024, 0, stream>>>(deg, offsets, cursor, dinv);
  k_fill<<<(N_EDGES+255)/256, 256, 0, stream>>>(ei, cursor, csr);
  k_gjoint<<<2500 + 1024 + 384, 256, 0, stream>>>(Xb, csr, offsets, deg, dinv, Pb,
                                                  W1, Wt1, W2, Wt2);
  k_gemm1f<<<dim3(D_HID/128, MP1/128), 256, 0, stream>>>(Pb, Wt1, b1, Wt2, G);
  k_gather2<<<N_NODES, 64, 0, stream>>>(G, csr, offsets, deg, dinv, b2, out);
}

// Round 9
// 240.616 us; speedup vs baseline: 1.3889x; 1.0040x over previous
//
#include <hip/hip_runtime.h>
#include <stdint.h>

#define N_NODES 10000
#define N_EDGES 320000
#define D_IN    512
#define D_HID   2048
#define N_CLS   40
#define MP1     10112   // 79*128 (GEMM1 M padding)
#define HSTR    136     // Hs row stride (shorts): 272B, breaks pow2 banks

typedef float f32x4  __attribute__((ext_vector_type(4)));
typedef short bf16x8 __attribute__((ext_vector_type(8)));
typedef unsigned short us8 __attribute__((ext_vector_type(8)));

__device__ inline unsigned short f2bf(float f){
  unsigned int u = __float_as_uint(f);
  u += 0x7fffu + ((u >> 16) & 1u);   // round-to-nearest-even
  return (unsigned short)(u >> 16);
}

__device__ inline float bf2f(unsigned short h){
  return __uint_as_float(((unsigned int)h) << 16);
}

__device__ inline void gl_lds16(const void* g, void* l){
  __builtin_amdgcn_global_load_lds((const __attribute__((address_space(1))) void*)g,
                                   (__attribute__((address_space(3))) void*)l, 16, 0, 0);
}

// ---------------- fused: x->bf16 cast + degree count ----------------
__global__ void k_prep0(const float* __restrict__ x, unsigned short* __restrict__ Xb,
                        const int* __restrict__ ei, int* __restrict__ deg){
  if (blockIdx.x < 2500){
    int idx = blockIdx.x*256 + threadIdx.x;
    const f32x4* x4 = (const f32x4*)x;
    f32x4 a = x4[idx*2], b = x4[idx*2+1];
    us8 o;
    o[0]=f2bf(a.x); o[1]=f2bf(a.y); o[2]=f2bf(a.z); o[3]=f2bf(a.w);
    o[4]=f2bf(b.x); o[5]=f2bf(b.y); o[6]=f2bf(b.z); o[7]=f2bf(b.w);
    *(us8*)(Xb + (size_t)idx*8) = o;
  } else {
    int e = (blockIdx.x - 2500)*256 + threadIdx.x;
    if (e < N_EDGES) atomicAdd(&deg[ei[N_EDGES + e]], 1);
  }
}

__global__ void k_scan(const int* __restrict__ deg, int* __restrict__ offsets,
                       int* __restrict__ cursor, float* __restrict__ dinv){
  __shared__ int sums[1024];
  const int t = threadIdx.x;
  const int CH = 10;
  int base = t*CH;
  int local[CH]; int s = 0;
  for (int j = 0; j < CH; j++){
    int v = (base + j < N_NODES) ? deg[base + j] : 0;
    local[j] = s; s += v;
    if (base + j < N_NODES) dinv[base + j] = rsqrtf((float)v + 1.0f);
  }
  sums[t] = s;
  __syncthreads();
  for (int off = 1; off < 1024; off <<= 1){
    int v = (t >= off) ? sums[t - off] : 0;
    __syncthreads();
    sums[t] += v;
    __syncthreads();
  }
  int pre = (t > 0) ? sums[t-1] : 0;
  for (int j = 0; j < CH; j++){
    int idx = base + j;
    if (idx < N_NODES){ int o = pre + local[j]; offsets[idx] = o; cursor[idx] = o; }
  }
}

__global__ void k_fill(const int* __restrict__ ei, int* __restrict__ cursor, int* __restrict__ csr_src){
  int e = blockIdx.x*256 + threadIdx.x;
  if (e < N_EDGES){
    int s = ei[e], d = ei[N_EDGES + e];
    int pos = atomicAdd(&cursor[d], 1);
    csr_src[pos] = s;
  }
}

// ---------------- fused: gather1 (blocks 0..2499) + weight prep (rest) ----------------
__global__ __launch_bounds__(256) void k_gjoint(const unsigned short* __restrict__ Xb,
                          const int* __restrict__ csr_src,
                          const int* __restrict__ offsets, const int* __restrict__ deg,
                          const float* __restrict__ dinv, unsigned short* __restrict__ Pb,
                          const float* __restrict__ W1, unsigned short* __restrict__ Wt1,
                          const float* __restrict__ W2, unsigned short* __restrict__ Wt2){
  __shared__ float tile[32][33];
  if (blockIdx.x < 2500){
    const int w    = threadIdx.x >> 6;
    const int lane = threadIdx.x & 63;
    const int i    = blockIdx.x*4 + w;
    const float di = dinv[i];
    float acc[8];
    us8 xi = *(const us8*)(Xb + (size_t)i*D_IN + lane*8);
    const float dii = di*di;
    #pragma unroll
    for (int r = 0; r < 8; r++) acc[r] = dii * bf2f(xi[r]);
    const int start = offsets[i], cnt = deg[i];
    for (int c0 = 0; c0 < cnt; c0 += 64){
      int m = cnt - c0; if (m > 64) m = 64;
      int s = 0; float cf = 0.0f;
      if (lane < m){ s = csr_src[start + c0 + lane]; cf = dinv[s]*di; }
      for (int j = 0; j < m; j++){
        int   sj = __shfl(s, j);
        float cj = __shfl(cf, j);
        us8 xr = *(const us8*)(Xb + (size_t)sj*D_IN + lane*8);
        #pragma unroll
        for (int r = 0; r < 8; r++) acc[r] += cj * bf2f(xr[r]);
      }
    }
    us8 o;
    #pragma unroll
    for (int r = 0; r < 8; r++) o[r] = f2bf(acc[r]);
    *(us8*)(Pb + (size_t)i*D_IN + lane*8) = o;
  } else if (blockIdx.x < 2500 + 1024){
    const int bb = blockIdx.x - 2500;
    const int n0 = (bb & 63)*32, k0 = (bb >> 6)*32;
    const int tx = threadIdx.x & 31, ty = threadIdx.x >> 5;
    for (int i = 0; i < 32; i += 8)
      tile[ty+i][tx] = W1[(size_t)(k0+ty+i)*D_HID + n0+tx];
    __syncthreads();
    for (int i = 0; i < 32; i += 8)
      Wt1[(size_t)(n0+ty+i)*D_IN + k0+tx] = f2bf(tile[tx][ty+i]);
  } else {
    int idx = (blockIdx.x - 3524)*256 + threadIdx.x;
    if (idx < 48*D_HID){
      int n = idx >> 11, k = idx & (D_HID-1);
      Wt2[idx] = (n < N_CLS) ? f2bf(W2[k*N_CLS + n]) : (unsigned short)0;
    }
  }
}

// ---------------- GEMM1+GEMM2 fused, double-buffered K-loop ----------------
// Grid (16 n-panels fast, 79 m-tiles): per-XCD B panels L2-pinned (R8-proven,
// FETCH 88->42MB). __launch_bounds__(256,4): cap unified V+A regs at 128 so
// 4 blocks/CU co-reside (R8 had 72V+~88A ~ 160 -> 3 blocks; barrier bubbles
// starved the LDS/MFMA pipes).
__global__ __launch_bounds__(256, 4) void k_gemm1f(const unsigned short* __restrict__ Pb,
                                                   const unsigned short* __restrict__ Wt1,
                                                   const float* __restrict__ b1,
                                                   const unsigned short* __restrict__ Wt2,
                                                   float* __restrict__ G){
  __shared__ short smem[128*HSTR];     // 34816 B; K-loop uses [0,32KB) as 2 bufs
  short* Hs = smem;
  const int t    = threadIdx.x;
  const int lane = t & 63;
  const int wid  = t >> 6;
  const int wm   = (wid >> 1)*64, wn = (wid & 1)*64;
  const int m0   = blockIdx.y*128, n0 = blockIdx.x*128;
  const int arow = t >> 2;
  const int akof = ((t & 3) ^ ((t >> 3) & 3))*8;  // swizzled source chunk
  const int fr   = lane & 15;
  const int q    = lane >> 4;
  const int sq8  = (q ^ ((fr >> 1) & 3))*8;       // swizzled read offset

  const unsigned short* ApA = Pb  + (size_t)(m0 +      arow)*D_IN + akof;
  const unsigned short* ApB = Pb  + (size_t)(m0 + 64 + arow)*D_IN + akof;
  const unsigned short* BpA = Wt1 + (size_t)(n0 +      arow)*D_IN + akof;
  const unsigned short* BpB = Wt1 + (size_t)(n0 + 64 + arow)*D_IN + akof;

  f32x4 acc[4][4] = {};
  // prologue: stage iter 0 into buf 0
  {
    short* As = smem;       short* Bs = smem + 4096;
    gl_lds16(ApA, As + t*8);  gl_lds16(ApB, As + 2048 + t*8);
    gl_lds16(BpA, Bs + t*8);  gl_lds16(BpB, Bs + 2048 + t*8);
  }
  #pragma unroll
  for (int ks = 0; ks < 16; ks++){
    if (ks < 15){
      short* As = smem + ((ks+1)&1)*8192;
      short* Bs = As + 4096;
      const int kb = (ks+1)*32;
      gl_lds16(ApA + kb, As + t*8);  gl_lds16(ApB + kb, As + 2048 + t*8);
      gl_lds16(BpA + kb, Bs + t*8);  gl_lds16(BpB + kb, Bs + 2048 + t*8);
      asm volatile("" ::: "memory");
      __builtin_amdgcn_s_waitcnt(0x0F74);   // vmcnt(4): current buf done, next in flight
    } else {
      asm volatile("" ::: "memory");
      __builtin_amdgcn_s_waitcnt(0x0F70);   // vmcnt(0): last buf
    }
    __builtin_amdgcn_s_barrier();
    asm volatile("" ::: "memory");
    const short* As = smem + (ks&1)*8192;
    const short* Bs = As + 4096;
    bf16x8 a[4], b[4];
    #pragma unroll
    for (int i = 0; i < 4; i++) a[i] = *(const bf16x8*)(As + (wm + i*16 + fr)*32 + sq8);
    #pragma unroll
    for (int j = 0; j < 4; j++) b[j] = *(const bf16x8*)(Bs + (wn + j*16 + fr)*32 + sq8);
    #pragma unroll
    for (int i = 0; i < 4; i++)
      #pragma unroll
      for (int j = 0; j < 4; j++)
        acc[i][j] = __builtin_amdgcn_mfma_f32_16x16x32_bf16(a[i], b[j], acc[i][j], 0, 0, 0);
    asm volatile("" ::: "memory");
    __builtin_amdgcn_s_barrier();           // reads of this buf done before overwrite
    asm volatile("" ::: "memory");
  }
  // epilogue stage A: bias+ReLU, H tile -> LDS bf16
  #pragma unroll
  for (int j = 0; j < 4; j++){
    int col = wn + j*16 + fr;
    float bias = b1[n0 + col];
    #pragma unroll
    for (int i = 0; i < 4; i++){
      int rbase = wm + i*16 + q*4;
      f32x4 v = acc[i][j];
      #pragma unroll
      for (int r = 0; r < 4; r++){
        float h = fmaxf(v[r] + bias, 0.0f);
        Hs[(rbase + r)*HSTR + col] = (short)f2bf(h);
      }
    }
  }
  __syncthreads();
  // epilogue stage B: G_partial = Hs @ Wt2[:, n0:n0+128]^T ; wave owns 32 rows
  f32x4 acc2[2][3] = {};
  for (int ks = 0; ks < 4; ks++){
    bf16x8 a2[2];
    #pragma unroll
    for (int i2 = 0; i2 < 2; i2++)
      a2[i2] = *(const bf16x8*)(Hs + (wid*32 + i2*16 + fr)*HSTR + ks*32 + q*8);
    #pragma unroll
    for (int j2 = 0; j2 < 3; j2++){
      bf16x8 b2 = *(const bf16x8*)(Wt2 + (size_t)(j2*16 + fr)*D_HID + n0 + ks*32 + q*8);
      #pragma unroll
      for (int i2 = 0; i2 < 2; i2++)
        acc2[i2][j2] = __builtin_amdgcn_mfma_f32_16x16x32_bf16(a2[i2], b2, acc2[i2][j2], 0, 0, 0);
    }
  }
  #pragma unroll
  for (int j2 = 0; j2 < 3; j2++){
    int col = j2*16 + fr;
    if (col < N_CLS){
      #pragma unroll
      for (int i2 = 0; i2 < 2; i2++){
        int rbase = m0 + wid*32 + i2*16 + q*4;
        f32x4 v = acc2[i2][j2];
        #pragma unroll
        for (int r = 0; r < 4; r++){
          int row = rbase + r;
          if (row < N_NODES)
            atomicAdd(&G[row*N_CLS + col], v[r]);
        }
      }
    }
  }
}

// ---------------- propagate(G) + b2 -> out ----------------
__global__ void k_gather2(const float* __restrict__ G, const int* __restrict__ csr_src,
                          const int* __restrict__ offsets, const int* __restrict__ deg,
                          const float* __restrict__ dinv, const float* __restrict__ b2,
                          float* __restrict__ out){
  __shared__ int   ssrc[64];
  __shared__ float scoef[64];
  const int i = blockIdx.x;
  const int t = threadIdx.x;
  const float di = dinv[i];
  const int start = offsets[i], cnt = deg[i];
  float acc = 0.0f;
  if (t < N_CLS) acc = di*di * G[i*N_CLS + t];
  for (int c0 = 0; c0 < cnt; c0 += 64){
    int m = cnt - c0; if (m > 64) m = 64;
    if (t < m){
      int s = csr_src[start + c0 + t];
      ssrc[t] = s; scoef[t] = dinv[s]*di;
    }
    __syncthreads();
    if (t < N_CLS)
      for (int j = 0; j < m; j++)
        acc += scoef[j] * G[ssrc[j]*N_CLS + t];
    __syncthreads();
  }
  if (t < N_CLS) out[i*N_CLS + t] = acc + b2[t];
}

extern "C" void kernel_launch(void* const* d_in, const int* in_sizes, int n_in,
                              void* d_out, int out_size, void* d_ws, size_t ws_size,
                              hipStream_t stream){
  const float* x  = (const float*)d_in[0];
  const int*   ei = (const int*)d_in[1];
  const float* W1 = (const float*)d_in[2];
  const float* b1 = (const float*)d_in[3];
  const float* W2 = (const float*)d_in[4];
  const float* b2 = (const float*)d_in[5];
  float* out = (float*)d_out;

  char* ws = (char*)d_ws;
  size_t off = 0;
  auto alloc = [&](size_t bytes) -> void* {
    void* p = ws + off; off += (bytes + 255) & ~(size_t)255; return p;
  };
  int*   deg     = (int*)alloc((size_t)N_NODES*4);
  float* dinv    = (float*)alloc((size_t)N_NODES*4);
  int*   offsets = (int*)alloc((size_t)N_NODES*4);
  int*   cursor  = (int*)alloc((size_t)N_NODES*4);
  int*   csr     = (int*)alloc((size_t)N_EDGES*4);
  unsigned short* Xb  = (unsigned short*)alloc((size_t)N_NODES*D_IN*2);
  unsigned short* Pb  = (unsigned short*)alloc((size_t)MP1*D_IN*2);
  unsigned short* Wt1 = (unsigned short*)alloc((size_t)D_HID*D_IN*2);
  unsigned short* Wt2 = (unsigned short*)alloc((size_t)48*D_HID*2);
  float* G = (float*)alloc((size_t)N_NODES*N_CLS*4);

  hipMemsetAsync(deg, 0, (size_t)N_NODES*4, stream);
  hipMemsetAsync(G,   0, (size_t)N_NODES*N_CLS*4, stream);

  k_prep0<<<2500 + 1250, 256, 0, stream>>>(x, Xb, ei, deg);
  k_scan<<<1, 1024, 0, stream>>>(deg, offsets, cursor, dinv);
  k_fill<<<(N_EDGES+255)/256, 256, 0, stream>>>(ei, cursor, csr);
  k_gjoint<<<2500 + 1024 + 384, 256, 0, stream>>>(Xb, csr, offsets, deg, dinv, Pb,
                                                  W1, Wt1, W2, Wt2);
  k_gemm1f<<<dim3(D_HID/128, MP1/128), 256, 0, stream>>>(Pb, Wt1, b1, Wt2, G);
  k_gather2<<<N_NODES, 64, 0, stream>>>(G, csr, offsets, deg, dinv, b2, out);
}